// Round 2
// baseline (767.829 us; speedup 1.0000x reference)
//
#include <hip/hip_runtime.h>
#include <hip/hip_bf16.h>

#define S_LEN 128
#define B_SZ  32
#define VOCAB 32000
#define EMB   32
#define HID   8
#define NROWS 4096   // S_LEN * B_SZ

// ---------------------------------------------------------------------------
// Kernel 1: embedding lookup + input projections for both directions (fp32).
// xpF[tok][j] = X[tok]·Wxf[:,j] + bias_x[j] + bias_hf[j]
// xpB[tok][j] = X[tok]·Wxb[:,j] + bias_x[j] + bias_hb[j]
// ---------------------------------------------------------------------------
__global__ __launch_bounds__(256) void xproj_kernel(
        const int* __restrict__ idx,
        const float* __restrict__ lookup,
        const float* __restrict__ wxf,
        const float* __restrict__ wxb,
        const float* __restrict__ bias_x,
        const float* __restrict__ bias_hf,
        const float* __restrict__ bias_hb,
        float* __restrict__ xpF, float* __restrict__ xpB) {
    int tok = blockIdx.x * blockDim.x + threadIdx.x;
    if (tok >= NROWS) return;
    int e = idx[tok];
    const float* xr = lookup + (size_t)e * EMB;
    float x[EMB];
    #pragma unroll
    for (int i = 0; i < EMB; ++i) x[i] = xr[i];
    #pragma unroll
    for (int j = 0; j < HID; ++j) {
        float bx = bias_x[j];
        float fa = bx + bias_hf[j];
        float fb = bx + bias_hb[j];
        #pragma unroll
        for (int e2 = 0; e2 < EMB; ++e2) {
            float xv = x[e2];
            fa += xv * wxf[e2 * HID + j];
            fb += xv * wxb[e2 * HID + j];
        }
        xpF[(size_t)tok * HID + j] = fa;
        xpB[(size_t)tok * HID + j] = fb;
    }
}

// ---------------------------------------------------------------------------
// Kernel 2: the two Elman scans (sequential in S). 512 lanes total over
// 8 blocks x 64 threads:  gtid = dir*256 + b*8 + j.
// Table semantics (shifted): store h BEFORE consuming x[s], walking forward
// for dir=0 and backward for dir=1. Hws[r][0:8]=fwd, [8:16]=bwd, fp32.
// ---------------------------------------------------------------------------
__global__ __launch_bounds__(64) void scan_kernel(
        const float* __restrict__ xpF,
        const float* __restrict__ xpB,
        const float* __restrict__ whf,
        const float* __restrict__ whb,
        const float* __restrict__ Hf0,
        const float* __restrict__ Hb0,
        float* __restrict__ Hws) {
    int gtid = blockIdx.x * 64 + threadIdx.x;
    int j   = gtid & 7;
    int b   = (gtid >> 3) & 31;
    int dir = gtid >> 8;

    const float* wh = dir ? whb : whf;
    float w[HID];
    #pragma unroll
    for (int k = 0; k < HID; ++k) w[k] = wh[k * HID + j];

    const float* xp = dir ? xpB : xpF;
    float h = dir ? Hb0[j] : Hf0[j];

    int s0 = dir ? (S_LEN - 1) : 0;
    float xv = xp[(size_t)(s0 * B_SZ + b) * HID + j];

    for (int step = 0; step < S_LEN; ++step) {
        int s = dir ? (S_LEN - 1 - step) : step;
        int r = s * B_SZ + b;
        // prefetch next step's x-projection (issues before the dep chain)
        float xv_next = 0.0f;
        if (step + 1 < S_LEN) {
            int sn = dir ? (S_LEN - 2 - step) : (step + 1);
            xv_next = xp[(size_t)(sn * B_SZ + b) * HID + j];
        }
        Hws[(size_t)r * 16 + dir * HID + j] = h;   // store pre-update state
        float acc = xv;
        #pragma unroll
        for (int k = 0; k < HID; ++k)
            acc += __shfl(h, k, 8) * w[k];
        // tanh(x) = 1 - 2/(e^{2x}+1)
        float ex = __expf(2.0f * acc);
        h = 1.0f - 2.0f * __builtin_amdgcn_rcpf(ex + 1.0f);
        xv = xv_next;
    }
}

// ---------------------------------------------------------------------------
// Kernel 3: transpose weight_o [16][32000] -> wo_t [32000][16] so pass A's
// uniform weight reads are contiguous (scalar-load friendly).
// ---------------------------------------------------------------------------
__global__ __launch_bounds__(256) void transpose_kernel(
        const float* __restrict__ wo, float* __restrict__ wo_t) {
    int v = blockIdx.x * blockDim.x + threadIdx.x;
    if (v >= VOCAB) return;
    float w[16];
    #pragma unroll
    for (int k = 0; k < 16; ++k) w[k] = wo[(size_t)k * VOCAB + v];
    float4* dst = reinterpret_cast<float4*>(wo_t + (size_t)v * 16);
    dst[0] = make_float4(w[0], w[1], w[2], w[3]);
    dst[1] = make_float4(w[4], w[5], w[6], w[7]);
    dst[2] = make_float4(w[8], w[9], w[10], w[11]);
    dst[3] = make_float4(w[12], w[13], w[14], w[15]);
}

// ---------------------------------------------------------------------------
// Kernel 4 (pass A): partial sums of exp(logits) per row. Thread owns a ROW
// (h[16] in VGPRs); loops over a 256-wide v-chunk. Weight/bias addresses are
// block-uniform -> scalar loads (SMEM pipe), VALU does only FMA+exp+add.
// |logit| <= ~0.1 so no max subtraction is needed.
// Zpart[chunk][row], 125 x 4096.
// ---------------------------------------------------------------------------
#define VCH_A 256
#define NCH_A (VOCAB / VCH_A)   // 125
__global__ __launch_bounds__(256) void passA_kernel(
        const float* __restrict__ Hws,
        const float* __restrict__ wo_t,
        const float* __restrict__ bias_o,
        float* __restrict__ Zpart) {
    int r = blockIdx.y * 256 + threadIdx.x;
    int v0 = blockIdx.x * VCH_A;

    float h[16];
    const float4* hr = reinterpret_cast<const float4*>(Hws + (size_t)r * 16);
    #pragma unroll
    for (int q = 0; q < 4; ++q) {
        float4 f = hr[q];
        h[4 * q + 0] = f.x; h[4 * q + 1] = f.y;
        h[4 * q + 2] = f.z; h[4 * q + 3] = f.w;
    }

    float z = 0.0f;
    for (int vv = 0; vv < VCH_A; ++vv) {
        const float* wt = wo_t + (size_t)(v0 + vv) * 16;   // block-uniform
        float acc = bias_o[v0 + vv];                        // block-uniform
        #pragma unroll
        for (int k = 0; k < 16; ++k) acc += h[k] * wt[k];
        z += __expf(acc);
    }
    Zpart[(size_t)blockIdx.x * NROWS + r] = z;
}

// ---------------------------------------------------------------------------
// Kernel 5: logZ[r] = log(sum over 125 chunk partials)
// ---------------------------------------------------------------------------
__global__ __launch_bounds__(256) void logz_kernel(
        const float* __restrict__ Zpart, float* __restrict__ logZ) {
    int r = blockIdx.x * blockDim.x + threadIdx.x;
    if (r >= NROWS) return;
    float s = 0.0f;
    for (int i = 0; i < NCH_A; ++i) s += Zpart[(size_t)i * NROWS + r];
    logZ[r] = logf(s);
}

// ---------------------------------------------------------------------------
// Kernel 6 (pass B): out[r][v] = logit - logZ[r], fp32, float4 stores.
// Thread owns 4 vocab columns (64 weight floats in VGPRs, amortized over
// MT_B rows); h row + logZ are block-uniform -> scalar loads.
// ---------------------------------------------------------------------------
#define MT_B 128
__global__ __launch_bounds__(256) void passB_kernel(
        const float* __restrict__ Hws,
        const float* __restrict__ wo,
        const float* __restrict__ bias_o,
        const float* __restrict__ logZ,
        float* __restrict__ out) {
    int t = threadIdx.x;
    int v = (blockIdx.x * 256 + t) * 4;
    if (v >= VOCAB) return;
    int r0 = blockIdx.y * MT_B;

    float4 w4[16];
    #pragma unroll
    for (int k = 0; k < 16; ++k)
        w4[k] = *reinterpret_cast<const float4*>(wo + (size_t)k * VOCAB + v);
    float4 bv = *reinterpret_cast<const float4*>(bias_o + v);

    for (int rr = 0; rr < MT_B; ++rr) {
        int r = r0 + rr;
        const float* hr = Hws + (size_t)r * 16;   // block-uniform
        float t0 = bv.x, t1 = bv.y, t2 = bv.z, t3 = bv.w;
        #pragma unroll
        for (int k = 0; k < 16; ++k) {
            float hk = hr[k];
            t0 += hk * w4[k].x;
            t1 += hk * w4[k].y;
            t2 += hk * w4[k].z;
            t3 += hk * w4[k].w;
        }
        float lz = logZ[r];                       // block-uniform
        float4 o = make_float4(t0 - lz, t1 - lz, t2 - lz, t3 - lz);
        *reinterpret_cast<float4*>(out + (size_t)r * VOCAB + v) = o;
    }
}

// ---------------------------------------------------------------------------
extern "C" void kernel_launch(void* const* d_in, const int* in_sizes, int n_in,
                              void* d_out, int out_size, void* d_ws, size_t ws_size,
                              hipStream_t stream) {
    const int*   idx     = (const int*)d_in[0];
    const float* lookup  = (const float*)d_in[1];
    const float* wxf     = (const float*)d_in[2];
    const float* whf     = (const float*)d_in[3];
    const float* wxb     = (const float*)d_in[4];
    const float* whb     = (const float*)d_in[5];
    const float* wo      = (const float*)d_in[6];
    const float* Hf0     = (const float*)d_in[7];
    const float* Hb0     = (const float*)d_in[8];
    const float* bias_x  = (const float*)d_in[9];
    const float* bias_hf = (const float*)d_in[10];
    const float* bias_hb = (const float*)d_in[11];
    const float* bias_o  = (const float*)d_in[12];
    float* out = (float*)d_out;

    float* ws    = (float*)d_ws;
    float* xpF   = ws;                  //  32768 floats
    float* xpB   = ws + 32768;          //  32768
    float* Hws   = ws + 65536;          //  65536 (4096 x 16)
    float* wo_t  = ws + 131072;         // 512000 (32000 x 16)
    float* Zpart = ws + 643072;         // 512000 (125 x 4096)
    float* logZ  = ws + 1155072;        //   4096
    // total ~4.64 MB of ws

    xproj_kernel<<<16, 256, 0, stream>>>(idx, lookup, wxf, wxb,
                                         bias_x, bias_hf, bias_hb, xpF, xpB);
    scan_kernel<<<8, 64, 0, stream>>>(xpF, xpB, whf, whb, Hf0, Hb0, Hws);
    transpose_kernel<<<125, 256, 0, stream>>>(wo, wo_t);
    passA_kernel<<<dim3(NCH_A, NROWS / 256), 256, 0, stream>>>(Hws, wo_t, bias_o, Zpart);
    logz_kernel<<<16, 256, 0, stream>>>(Zpart, logZ);
    passB_kernel<<<dim3(32, NROWS / MT_B), 256, 0, stream>>>(Hws, wo, bias_o, logZ, out);
}

// Round 3
// 684.540 us; speedup vs baseline: 1.1217x; 1.1217x over previous
//
#include <hip/hip_runtime.h>
#include <hip/hip_bf16.h>

#define S_LEN 128
#define B_SZ  32
#define VOCAB 32000
#define EMB   32
#define HID   8
#define NROWS 4096   // S_LEN * B_SZ

typedef float v2f __attribute__((ext_vector_type(2)));

#if defined(__has_builtin) && __has_builtin(__builtin_elementwise_fma)
__device__ __forceinline__ v2f fma2(v2f a, v2f b, v2f c) {
    return __builtin_elementwise_fma(a, b, c);
}
#else
__device__ __forceinline__ v2f fma2(v2f a, v2f b, v2f c) {
    v2f r; r.x = fmaf(a.x, b.x, c.x); r.y = fmaf(a.y, b.y, c.y); return r;
}
#endif

// ---------------------------------------------------------------------------
// Kernel 1: embedding lookup + input projections for both directions (fp32).
// xpF[tok][j] = X[tok]·Wxf[:,j] + bias_x[j] + bias_hf[j]
// xpB[tok][j] = X[tok]·Wxb[:,j] + bias_x[j] + bias_hb[j]
// ---------------------------------------------------------------------------
__global__ __launch_bounds__(256) void xproj_kernel(
        const int* __restrict__ idx,
        const float* __restrict__ lookup,
        const float* __restrict__ wxf,
        const float* __restrict__ wxb,
        const float* __restrict__ bias_x,
        const float* __restrict__ bias_hf,
        const float* __restrict__ bias_hb,
        float* __restrict__ xpF, float* __restrict__ xpB) {
    int tok = blockIdx.x * blockDim.x + threadIdx.x;
    if (tok >= NROWS) return;
    int e = idx[tok];
    const float* xr = lookup + (size_t)e * EMB;
    float x[EMB];
    #pragma unroll
    for (int i = 0; i < EMB; ++i) x[i] = xr[i];
    #pragma unroll
    for (int j = 0; j < HID; ++j) {
        float bx = bias_x[j];
        float fa = bx + bias_hf[j];
        float fb = bx + bias_hb[j];
        #pragma unroll
        for (int e2 = 0; e2 < EMB; ++e2) {
            float xv = x[e2];
            fa += xv * wxf[e2 * HID + j];
            fb += xv * wxb[e2 * HID + j];
        }
        xpF[(size_t)tok * HID + j] = fa;
        xpB[(size_t)tok * HID + j] = fb;
    }
}

// ---------------------------------------------------------------------------
// Kernel 2: the two Elman scans (sequential in S). 512 lanes over 8 blocks
// x 64 threads: gtid = dir*256 + b*8 + j. Store h BEFORE consuming x[s],
// walking forward for dir=0 and backward for dir=1.
// Hws[r][0:8]=fwd, [8:16]=bwd, fp32.
// ---------------------------------------------------------------------------
__global__ __launch_bounds__(64) void scan_kernel(
        const float* __restrict__ xpF,
        const float* __restrict__ xpB,
        const float* __restrict__ whf,
        const float* __restrict__ whb,
        const float* __restrict__ Hf0,
        const float* __restrict__ Hb0,
        float* __restrict__ Hws) {
    int gtid = blockIdx.x * 64 + threadIdx.x;
    int j   = gtid & 7;
    int b   = (gtid >> 3) & 31;
    int dir = gtid >> 8;

    const float* wh = dir ? whb : whf;
    float w[HID];
    #pragma unroll
    for (int k = 0; k < HID; ++k) w[k] = wh[k * HID + j];

    const float* xp = dir ? xpB : xpF;
    float h = dir ? Hb0[j] : Hf0[j];

    int s0 = dir ? (S_LEN - 1) : 0;
    float xv = xp[(size_t)(s0 * B_SZ + b) * HID + j];

    for (int step = 0; step < S_LEN; ++step) {
        int s = dir ? (S_LEN - 1 - step) : step;
        int r = s * B_SZ + b;
        float xv_next = 0.0f;
        if (step + 1 < S_LEN) {
            int sn = dir ? (S_LEN - 2 - step) : (step + 1);
            xv_next = xp[(size_t)(sn * B_SZ + b) * HID + j];
        }
        Hws[(size_t)r * 16 + dir * HID + j] = h;   // store pre-update state
        float acc = xv;
        #pragma unroll
        for (int k = 0; k < HID; ++k)
            acc += __shfl(h, k, 8) * w[k];
        // tanh(x) = 1 - 2/(e^{2x}+1)
        float ex = __expf(2.0f * acc);
        h = 1.0f - 2.0f * __builtin_amdgcn_rcpf(ex + 1.0f);
        xv = xv_next;
    }
}

// ---------------------------------------------------------------------------
// Kernel 3: repack weight_o [16][32000] -> wo_p [16000][16][2]
// (adjacent vocab columns interleaved per k) so pass A's uniform weight
// reads are contiguous AND pair-packed for v_pk_fma_f32.
// ---------------------------------------------------------------------------
__global__ __launch_bounds__(256) void repack_kernel(
        const float* __restrict__ wo, float* __restrict__ wo_p) {
    int v2 = blockIdx.x * blockDim.x + threadIdx.x;
    if (v2 >= VOCAB / 2) return;
    float2 buf[16];
    #pragma unroll
    for (int k = 0; k < 16; ++k)
        buf[k] = *reinterpret_cast<const float2*>(wo + (size_t)k * VOCAB + 2 * v2);
    float4* dst = reinterpret_cast<float4*>(wo_p + (size_t)v2 * 32);
    #pragma unroll
    for (int q = 0; q < 8; ++q)
        dst[q] = make_float4(buf[2 * q].x, buf[2 * q].y,
                             buf[2 * q + 1].x, buf[2 * q + 1].y);
}

// ---------------------------------------------------------------------------
// Kernel 4 (pass A): partial sums of exp(logits) per row. Thread owns a ROW
// (h[16] in VGPRs); loops over a 256-wide v-chunk as 128 packed pairs.
// Weight/bias addresses are block-uniform -> scalar loads; VALU does
// 16 v_pk_fma + 2 exp + adds per pair. |logit| <= ~0.1 so no max needed.
// Zpart[chunk][row], 125 x 4096.
// ---------------------------------------------------------------------------
#define VCH_A 256
#define NCH_A (VOCAB / VCH_A)   // 125
__global__ __launch_bounds__(256) void passA_kernel(
        const float* __restrict__ Hws,
        const float* __restrict__ wo_p,
        const float* __restrict__ bias_o,
        float* __restrict__ Zpart) {
    int r = blockIdx.y * 256 + threadIdx.x;
    int p0 = blockIdx.x * (VCH_A / 2);   // pair-index base

    float h[16];
    const float4* hr4 = reinterpret_cast<const float4*>(Hws + (size_t)r * 16);
    #pragma unroll
    for (int q = 0; q < 4; ++q) {
        float4 f = hr4[q];
        h[4 * q + 0] = f.x; h[4 * q + 1] = f.y;
        h[4 * q + 2] = f.z; h[4 * q + 3] = f.w;
    }

    float z = 0.0f;
    #pragma unroll 2
    for (int p = 0; p < VCH_A / 2; ++p) {
        const v2f* wp = reinterpret_cast<const v2f*>(wo_p + (size_t)(p0 + p) * 32);
        float2 bb = *reinterpret_cast<const float2*>(bias_o + (size_t)(p0 + p) * 2);
        v2f acc; acc.x = bb.x; acc.y = bb.y;
        #pragma unroll
        for (int k = 0; k < 16; ++k) {
            v2f hk; hk.x = h[k]; hk.y = h[k];
            acc = fma2(hk, wp[k], acc);
        }
        z += __expf(acc.x) + __expf(acc.y);
    }
    Zpart[(size_t)blockIdx.x * NROWS + r] = z;
}

// ---------------------------------------------------------------------------
// Kernel 5: logZ[r] = log(sum over 125 chunk partials)
// ---------------------------------------------------------------------------
__global__ __launch_bounds__(256) void logz_kernel(
        const float* __restrict__ Zpart, float* __restrict__ logZ) {
    int r = blockIdx.x * blockDim.x + threadIdx.x;
    if (r >= NROWS) return;
    float s = 0.0f;
    for (int i = 0; i < NCH_A; ++i) s += Zpart[(size_t)i * NROWS + r];
    logZ[r] = logf(s);
}

// ---------------------------------------------------------------------------
// Kernel 6 (pass B): out[r][v] = logit - logZ[r], fp32, float4 stores.
// Thread owns 4 vocab columns as two packed pairs (64 weight floats in
// VGPRs, amortized over MT_B rows); h row + logZ are block-uniform ->
// scalar loads.
// ---------------------------------------------------------------------------
#define MT_B 128
__global__ __launch_bounds__(256) void passB_kernel(
        const float* __restrict__ Hws,
        const float* __restrict__ wo,
        const float* __restrict__ bias_o,
        const float* __restrict__ logZ,
        float* __restrict__ out) {
    int t = threadIdx.x;
    int v = (blockIdx.x * 256 + t) * 4;
    if (v >= VOCAB) return;
    int r0 = blockIdx.y * MT_B;

    v2f w01[16], w23[16];
    #pragma unroll
    for (int k = 0; k < 16; ++k) {
        float4 w4 = *reinterpret_cast<const float4*>(wo + (size_t)k * VOCAB + v);
        w01[k].x = w4.x; w01[k].y = w4.y;
        w23[k].x = w4.z; w23[k].y = w4.w;
    }
    float4 bv = *reinterpret_cast<const float4*>(bias_o + v);
    v2f b01; b01.x = bv.x; b01.y = bv.y;
    v2f b23; b23.x = bv.z; b23.y = bv.w;

    #pragma unroll 2
    for (int rr = 0; rr < MT_B; ++rr) {
        int r = r0 + rr;
        const float* hr = Hws + (size_t)r * 16;   // block-uniform
        v2f t01 = b01, t23 = b23;
        #pragma unroll
        for (int k = 0; k < 16; ++k) {
            float hk = hr[k];
            v2f hk2; hk2.x = hk; hk2.y = hk;
            t01 = fma2(hk2, w01[k], t01);
            t23 = fma2(hk2, w23[k], t23);
        }
        float lz = logZ[r];                       // block-uniform
        float4 o = make_float4(t01.x - lz, t01.y - lz, t23.x - lz, t23.y - lz);
        *reinterpret_cast<float4*>(out + (size_t)r * VOCAB + v) = o;
    }
}

// ---------------------------------------------------------------------------
extern "C" void kernel_launch(void* const* d_in, const int* in_sizes, int n_in,
                              void* d_out, int out_size, void* d_ws, size_t ws_size,
                              hipStream_t stream) {
    const int*   idx     = (const int*)d_in[0];
    const float* lookup  = (const float*)d_in[1];
    const float* wxf     = (const float*)d_in[2];
    const float* whf     = (const float*)d_in[3];
    const float* wxb     = (const float*)d_in[4];
    const float* whb     = (const float*)d_in[5];
    const float* wo      = (const float*)d_in[6];
    const float* Hf0     = (const float*)d_in[7];
    const float* Hb0     = (const float*)d_in[8];
    const float* bias_x  = (const float*)d_in[9];
    const float* bias_hf = (const float*)d_in[10];
    const float* bias_hb = (const float*)d_in[11];
    const float* bias_o  = (const float*)d_in[12];
    float* out = (float*)d_out;

    float* ws    = (float*)d_ws;
    float* xpF   = ws;                  //  32768 floats
    float* xpB   = ws + 32768;          //  32768
    float* Hws   = ws + 65536;          //  65536 (4096 x 16)
    float* wo_p  = ws + 131072;         // 512000 (16000 x 16 x 2)
    float* Zpart = ws + 643072;         // 512000 (125 x 4096)
    float* logZ  = ws + 1155072;        //   4096
    // total ~4.64 MB of ws

    xproj_kernel<<<16, 256, 0, stream>>>(idx, lookup, wxf, wxb,
                                         bias_x, bias_hf, bias_hb, xpF, xpB);
    scan_kernel<<<8, 64, 0, stream>>>(xpF, xpB, whf, whb, Hf0, Hb0, Hws);
    repack_kernel<<<63, 256, 0, stream>>>(wo, wo_p);
    passA_kernel<<<dim3(NCH_A, NROWS / 256), 256, 0, stream>>>(Hws, wo_p, bias_o, Zpart);
    logz_kernel<<<16, 256, 0, stream>>>(Zpart, logZ);
    passB_kernel<<<dim3(32, NROWS / MT_B), 256, 0, stream>>>(Hws, wo, bias_o, logZ, out);
}